// Round 3
// baseline (417.926 us; speedup 1.0000x reference)
//
#include <hip/hip_runtime.h>
#include <cstdint>
#include <cstddef>

using u16 = unsigned short;
using u32 = unsigned int;

typedef short short8 __attribute__((ext_vector_type(8)));
typedef float f32x4 __attribute__((ext_vector_type(4)));

// ---------- dtype helpers ----------
__device__ __forceinline__ float bf2f(u16 h) { return __uint_as_float(((u32)h) << 16); }
__device__ __forceinline__ u16 f2bf(float f) {
    u32 u = __float_as_uint(f);
    u += 0x7FFFu + ((u >> 16) & 1u);   // RNE
    return (u16)(u >> 16);
}
__device__ __forceinline__ float to_f(float v) { return v; }
__device__ __forceinline__ float to_f(u16 v) { return bf2f(v); }

template <typename T> struct OutCvt;
template <> struct OutCvt<float> { static __device__ __forceinline__ float cvt(float v) { return v; } };
template <> struct OutCvt<u16>   { static __device__ __forceinline__ u16   cvt(float v) { return f2bf(v); } };

// load 8 consecutive elements as f32 (16B-aligned at all call sites)
__device__ __forceinline__ void load8(const float* p, float* v) {
    float4 a = ((const float4*)p)[0];
    float4 b = ((const float4*)p)[1];
    v[0]=a.x; v[1]=a.y; v[2]=a.z; v[3]=a.w;
    v[4]=b.x; v[5]=b.y; v[6]=b.z; v[7]=b.w;
}
__device__ __forceinline__ void load8(const u16* p, float* v) {
    uint4 u = *(const uint4*)p;
    v[0]=__uint_as_float(u.x << 16); v[1]=__uint_as_float(u.x & 0xFFFF0000u);
    v[2]=__uint_as_float(u.y << 16); v[3]=__uint_as_float(u.y & 0xFFFF0000u);
    v[4]=__uint_as_float(u.z << 16); v[5]=__uint_as_float(u.z & 0xFFFF0000u);
    v[6]=__uint_as_float(u.w << 16); v[7]=__uint_as_float(u.w & 0xFFFF0000u);
}
// store 8 f32 values as TO
__device__ __forceinline__ void store8(float* p, const float* v) {
    ((float4*)p)[0] = make_float4(v[0], v[1], v[2], v[3]);
    ((float4*)p)[1] = make_float4(v[4], v[5], v[6], v[7]);
}
__device__ __forceinline__ void store8(u16* p, const float* v) {
    uint4 w;
    w.x = (u32)f2bf(v[0]) | ((u32)f2bf(v[1]) << 16);
    w.y = (u32)f2bf(v[2]) | ((u32)f2bf(v[3]) << 16);
    w.z = (u32)f2bf(v[4]) | ((u32)f2bf(v[5]) << 16);
    w.w = (u32)f2bf(v[6]) | ((u32)f2bf(v[7]) << 16);
    *(uint4*)p = w;
}
// 16B bf16x8 loads (global / LDS)
__device__ __forceinline__ short8 ld8b(const u16* p) {
    union { uint4 u; short8 s; } c;
    c.u = *(const uint4*)p;
    return c.s;
}

// ---------- 0. runtime dtype detection ----------
// flags[0]: 1 = float tensors are bf16, 0 = f32.  flags[1]: edge-index stride
// in 32-bit words (1 = int32, 2 = int64 low word).
__global__ __launch_bounds__(64) void detect_kernel(const u16* xraw, const u32* idxraw, int* flags) {
    if (threadIdx.x == 0 && blockIdx.x == 0) {
        int big = 0;
        for (int i = 0; i < 256; ++i) {
            int ex = (xraw[i] >> 7) & 0xFF;
            if (ex >= 0x90) big++;          // |v| >= 2^17 impossible for bf16 N(0,1) data
        }
        flags[0] = (big == 0) ? 1 : 0;
        int nz = 0;
        for (int i = 1; i < 256; i += 2) if (idxraw[i] != 0u) nz++;
        flags[1] = (nz == 0) ? 2 : 1;       // all-high-words-zero -> int64
    }
}

// ---------- 1. CSR build (atomic decoupled from the scatter store) ----------
__global__ __launch_bounds__(256) void hist_kernel(const int* idx, const int* __restrict__ flags,
                                                   int* cnt, int* within, int E) {
    const int e = blockIdx.x * blockDim.x + threadIdx.x;
    if (e >= E) return;
    const int stride = flags[1];
    const int d = idx[(size_t)(E + e) * stride];
    within[e] = atomicAdd(&cnt[d], 1);
}

#define SCAN_THREADS 1024
__global__ __launch_bounds__(SCAN_THREADS) void scan_kernel(const int* __restrict__ cnt,
                                                            int* row_ptr, int n) {
    __shared__ int sums[SCAN_THREADS];
    const int tid = threadIdx.x;
    const int chunk = (n + SCAN_THREADS - 1) / SCAN_THREADS;
    const int begin = tid * chunk;
    const int end = min(begin + chunk, n);
    int s = 0;
    for (int i = begin; i < end; ++i) s += cnt[i];
    sums[tid] = s;
    __syncthreads();
    for (int off = 1; off < SCAN_THREADS; off <<= 1) {
        int v = (tid >= off) ? sums[tid - off] : 0;
        __syncthreads();
        sums[tid] += v;
        __syncthreads();
    }
    int run = (tid == 0) ? 0 : sums[tid - 1];
    for (int i = begin; i < end; ++i) { row_ptr[i] = run; run += cnt[i]; }
    if (end == n) row_ptr[n] = run;
}

__global__ __launch_bounds__(256) void scatter_kernel(const int* idx, const int* __restrict__ flags,
                                                      const int* __restrict__ row_ptr,
                                                      const int* __restrict__ within,
                                                      int* ssrc, int E) {
    const int e = blockIdx.x * blockDim.x + threadIdx.x;
    if (e >= E) return;
    const int stride = flags[1];
    const int s = idx[(size_t)e * stride];
    const int d = idx[(size_t)(E + e) * stride];
    ssrc[row_ptr[d] + within[e]] = s;
}

// ---------- 2. layer-1 mean aggregation (wave per node, 8 f32 per lane) ----------
template <typename T, typename TO, int D>
__global__ __launch_bounds__(256) void agg_kernel(const T* __restrict__ feat,
                                                  const int* __restrict__ row_ptr,
                                                  const int* __restrict__ ssrc,
                                                  TO* __restrict__ out,
                                                  const int* __restrict__ flags, int n, int mode) {
    if (mode >= 0 && flags[0] != mode) return;
    constexpr int LPN = D / 8;
    constexpr int G = 64 / LPN;
    const int lane = threadIdx.x & 63;
    const int wid = (blockIdx.x * blockDim.x + threadIdx.x) >> 6;
    const int nw = (gridDim.x * blockDim.x) >> 6;
    const int g = lane / LPN;
    const int q = lane % LPN;
    for (int i = wid; i < n; i += nw) {
        const int rb = row_ptr[i], re = row_ptr[i + 1];
        float acc[8];
        #pragma unroll
        for (int k = 0; k < 8; ++k) acc[k] = 0.f;
        for (int e = rb + g; e < re; e += G) {
            int s = ssrc[e];
            float v[8];
            load8(feat + (size_t)s * D + q * 8, v);
            #pragma unroll
            for (int k = 0; k < 8; ++k) acc[k] += v[k];
        }
        #pragma unroll
        for (int m = LPN; m < 64; m <<= 1) {
            #pragma unroll
            for (int k = 0; k < 8; ++k) acc[k] += __shfl_xor(acc[k], m, 64);
        }
        if (g == 0) {
            float inv = 1.0f / (float)max(re - rb, 1);
            #pragma unroll
            for (int k = 0; k < 8; ++k) acc[k] *= inv;
            store8(out + (size_t)i * D + q * 8, acc);
        }
    }
}

// ---------- 3a. layer-1 MFMA path (bf16 mode only) ----------
// h1 = relu([A1|x] @ [W1l|W1r].T + b1);  z2 = bf16(h1@W2l.T);  r2 = b2 + h1@W2r.T
// Block = 4 waves = 64 nodes; wave w owns nodes [tile*64+w*16, +16).
// mfma_f32_16x16x32_bf16: A[m=lane&15][k=quad*8+j]; B[n=lane&15][k=quad*8+j];
// D col=lane&15 (n), row=quad*4+reg (m).   [per m89/m91/m120]
__global__ __launch_bounds__(256) void layer1_mfma_kernel(
    const u16* __restrict__ A1, const u16* __restrict__ x,
    const u16* __restrict__ W1l, const u16* __restrict__ b1,
    const u16* __restrict__ W1r, const u16* __restrict__ W2l,
    const u16* __restrict__ b2, const u16* __restrict__ W2r,
    u16* __restrict__ z2, float* __restrict__ r2,
    const int* __restrict__ flags, int n)
{
    if (flags[0] != 1) return;
    __shared__ alignas(16) u16 w1s[64 * 136];   // [ch][128 k] pad->136 (2-way banks = free)
    __shared__ alignas(16) u16 w2s[64 * 72];    // [out-ch][64 k] pad->72
    __shared__ alignas(16) u16 h1s[64 * 72];    // [node][64 ch] pad->72, per-wave private 16 rows

    const int t = threadIdx.x;
    // stage weights (coalesced 16B chunks)
    #pragma unroll
    for (int i = 0; i < 2; ++i) {
        int c = t + i * 256;                        // 512 chunks of 8 elems
        int ch = c >> 3, oct = c & 7;
        *(uint4*)&w1s[ch * 136 + oct * 8]      = *(const uint4*)&W1l[ch * 64 + oct * 8];
        *(uint4*)&w1s[ch * 136 + 64 + oct * 8] = *(const uint4*)&W1r[ch * 64 + oct * 8];
    }
    {
        int ch = t >> 3, oct = t & 7;               // 256 chunks cover 32x64
        *(uint4*)&w2s[ch * 72 + oct * 8]        = *(const uint4*)&W2l[ch * 64 + oct * 8];
        *(uint4*)&w2s[(ch + 32) * 72 + oct * 8] = *(const uint4*)&W2r[ch * 64 + oct * 8];
    }
    __syncthreads();

    const int lane = t & 63;
    const int wv = t >> 6;
    const int m = lane & 15, quad = lane >> 4;
    const int base = blockIdx.x * 64 + wv * 16;

    // A fragments for GEMM1 (k = [A1(64) | x(64)])
    const int nodeA = min(base + m, n - 1);
    const u16* arow = A1 + (size_t)nodeA * 64;
    const u16* xrow = x + (size_t)nodeA * 64;
    short8 a[4];
    a[0] = ld8b(arow + quad * 8);
    a[1] = ld8b(arow + 32 + quad * 8);
    a[2] = ld8b(xrow + quad * 8);
    a[3] = ld8b(xrow + 32 + quad * 8);

    // GEMM1 -> h1 tile into LDS (bf16)
    #pragma unroll
    for (int ni = 0; ni < 4; ++ni) {
        f32x4 acc = {0.f, 0.f, 0.f, 0.f};
        #pragma unroll
        for (int kc = 0; kc < 4; ++kc) {
            short8 b = ld8b(&w1s[(ni * 16 + m) * 136 + kc * 32 + quad * 8]);
            acc = __builtin_amdgcn_mfma_f32_16x16x32_bf16(a[kc], b, acc, 0, 0, 0);
        }
        const float bias = bf2f(b1[ni * 16 + m]);
        #pragma unroll
        for (int r = 0; r < 4; ++r) {
            float h = fmaxf(acc[r] + bias, 0.0f);
            h1s[(wv * 16 + quad * 4 + r) * 72 + ni * 16 + m] = f2bf(h);
        }
    }
    // same-wave LDS RAW: compiler inserts lgkmcnt waits; region is wave-private.

    short8 a2[2];
    a2[0] = ld8b(&h1s[(wv * 16 + m) * 72 + quad * 8]);
    a2[1] = ld8b(&h1s[(wv * 16 + m) * 72 + 32 + quad * 8]);

    #pragma unroll
    for (int ni = 0; ni < 4; ++ni) {
        f32x4 acc = {0.f, 0.f, 0.f, 0.f};
        #pragma unroll
        for (int kc = 0; kc < 2; ++kc) {
            short8 b = ld8b(&w2s[(ni * 16 + m) * 72 + kc * 32 + quad * 8]);
            acc = __builtin_amdgcn_mfma_f32_16x16x32_bf16(a2[kc], b, acc, 0, 0, 0);
        }
        if (ni < 2) {               // z2 channels 0..31 (no bias)
            const int ch = ni * 16 + m;
            #pragma unroll
            for (int r = 0; r < 4; ++r) {
                int node = base + quad * 4 + r;
                if (node < n) z2[(size_t)node * 32 + ch] = f2bf(acc[r]);
            }
        } else {                    // r2 channels 0..31 (+b2)
            const int ch = (ni - 2) * 16 + m;
            const float bias = bf2f(b2[ch]);
            #pragma unroll
            for (int r = 0; r < 4; ++r) {
                int node = base + quad * 4 + r;
                if (node < n) r2[(size_t)node * 32 + ch] = acc[r] + bias;
            }
        }
    }
}

// ---------- 3b. layer-1 f32 fallback (vector; dead when inputs are bf16) ----------
__global__ __launch_bounds__(256, 2) void layer1_f32_kernel(
    const float* __restrict__ A1, const float* __restrict__ x,
    const float* __restrict__ W1l, const float* __restrict__ b1,
    const float* __restrict__ W1r, const float* __restrict__ W2l,
    const float* __restrict__ b2, const float* __restrict__ W2r,
    u16* __restrict__ z2, float* __restrict__ r2,
    const int* __restrict__ flags, int n)
{
    if (flags[0] != 0) return;
    const int lane = threadIdx.x & 63;
    const int wid = (blockIdx.x * blockDim.x + threadIdx.x) >> 6;
    const int nw = (gridDim.x * blockDim.x) >> 6;

    float wl[64], wr[64], w2[64];
    #pragma unroll
    for (int k8 = 0; k8 < 8; ++k8) {
        load8(W1l + (size_t)lane * 64 + k8 * 8, &wl[k8 * 8]);
        load8(W1r + (size_t)lane * 64 + k8 * 8, &wr[k8 * 8]);
    }
    const float* w2src = (lane < 32) ? (W2l + (size_t)lane * 64) : (W2r + (size_t)(lane - 32) * 64);
    #pragma unroll
    for (int k8 = 0; k8 < 8; ++k8) load8(w2src + k8 * 8, &w2[k8 * 8]);
    const float b1c = b1[lane];
    const float zinit = (lane < 32) ? 0.0f : b2[lane - 32];

    for (int i = wid; i < n; i += nw) {
        const float* arow = A1 + (size_t)i * 64;
        const float* xrow = x + (size_t)i * 64;
        float p0 = 0.f, p1 = 0.f, p2 = 0.f, p3 = 0.f;   // 4 partials to break the chain
        #pragma unroll
        for (int k8 = 0; k8 < 8; ++k8) {
            float av[8], xv[8];
            load8(arow + k8 * 8, av);
            load8(xrow + k8 * 8, xv);
            p0 += av[0]*wl[k8*8+0] + xv[0]*wr[k8*8+0] + av[4]*wl[k8*8+4] + xv[4]*wr[k8*8+4];
            p1 += av[1]*wl[k8*8+1] + xv[1]*wr[k8*8+1] + av[5]*wl[k8*8+5] + xv[5]*wr[k8*8+5];
            p2 += av[2]*wl[k8*8+2] + xv[2]*wr[k8*8+2] + av[6]*wl[k8*8+6] + xv[6]*wr[k8*8+6];
            p3 += av[3]*wl[k8*8+3] + xv[3]*wr[k8*8+3] + av[7]*wl[k8*8+7] + xv[7]*wr[k8*8+7];
        }
        const float h1 = fmaxf((p0 + p1) + (p2 + p3) + b1c, 0.0f);
        float q0 = zinit, q1 = 0.f, q2 = 0.f, q3 = 0.f;
        #pragma unroll
        for (int c = 0; c < 64; c += 4) {
            q0 = fmaf(__int_as_float(__builtin_amdgcn_readlane(__float_as_int(h1), c)),     w2[c],     q0);
            q1 = fmaf(__int_as_float(__builtin_amdgcn_readlane(__float_as_int(h1), c + 1)), w2[c + 1], q1);
            q2 = fmaf(__int_as_float(__builtin_amdgcn_readlane(__float_as_int(h1), c + 2)), w2[c + 2], q2);
            q3 = fmaf(__int_as_float(__builtin_amdgcn_readlane(__float_as_int(h1), c + 3)), w2[c + 3], q3);
        }
        const float accz = (q0 + q1) + (q2 + q3);
        if (lane < 32) z2[(size_t)i * 32 + lane] = f2bf(accz);
        else           r2[(size_t)i * 32 + (lane - 32)] = accz;
    }
}

// ---------- 4. fused layer-2 agg + epilogue ----------
template <typename TW, typename TOut>
__global__ __launch_bounds__(256) void layer2_final_kernel(
    const u16* __restrict__ z2, const float* __restrict__ r2,
    const int* __restrict__ row_ptr, const int* __restrict__ ssrc,
    const TW* __restrict__ Wlin, const TW* __restrict__ blin,
    TOut* __restrict__ out, const int* __restrict__ flags, int n, int mode)
{
    if (flags[0] != mode) return;
    const int lane = threadIdx.x & 63;
    const int wid = (blockIdx.x * blockDim.x + threadIdx.x) >> 6;
    const int nw = (gridDim.x * blockDim.x) >> 6;
    const int g = lane >> 2;
    const int q = lane & 3;
    float wlin8[8];
    load8(Wlin + q * 8, wlin8);
    const float bl = to_f(blin[0]);
    for (int i = wid; i < n; i += nw) {
        const int rb = row_ptr[i], re = row_ptr[i + 1];
        float acc[8];
        #pragma unroll
        for (int k = 0; k < 8; ++k) acc[k] = 0.f;
        for (int e = rb + g; e < re; e += 16) {
            int s = ssrc[e];
            float v[8];
            load8(z2 + (size_t)s * 32 + q * 8, v);
            #pragma unroll
            for (int k = 0; k < 8; ++k) acc[k] += v[k];
        }
        #pragma unroll
        for (int m = 4; m < 64; m <<= 1) {
            #pragma unroll
            for (int k = 0; k < 8; ++k) acc[k] += __shfl_xor(acc[k], m, 64);
        }
        float partial = 0.0f;
        if (g == 0) {
            const float inv = 1.0f / (float)max(re - rb, 1);
            float r2v[8];
            load8(r2 + (size_t)i * 32 + q * 8, r2v);
            #pragma unroll
            for (int k = 0; k < 8; ++k)
                partial += fmaxf(fmaf(acc[k], inv, r2v[k]), 0.0f) * wlin8[k];
        }
        partial += __shfl_xor(partial, 1, 64);
        partial += __shfl_xor(partial, 2, 64);
        if (lane == 0) out[i] = OutCvt<TOut>::cvt(partial + bl);
    }
}

// ---------- host ----------
extern "C" void kernel_launch(void* const* d_in, const int* in_sizes, int n_in,
                              void* d_out, int out_size, void* d_ws, size_t ws_size,
                              hipStream_t stream) {
    (void)n_in; (void)out_size; (void)ws_size;
    const int N = in_sizes[0] / 64;
    const int E = in_sizes[1] / 2;

    char* ws = (char*)d_ws;
    size_t off = 0;
    auto alloc = [&](size_t bytes) -> void* {
        void* p = ws + off;
        off += (bytes + 255) & ~(size_t)255;
        return p;
    };
    int*   flags   = (int*)alloc(16);
    int*   cnt     = (int*)alloc((size_t)N * 4);
    int*   within  = (int*)alloc((size_t)E * 4);
    int*   row_ptr = (int*)alloc(((size_t)N + 1) * 4);
    int*   ssrc    = (int*)alloc((size_t)E * 4);
    void*  A1      = alloc((size_t)N * 64 * 4);   // f32 (mode 0) OR bf16 (mode 1), mutually exclusive
    u16*   z2      = (u16*)alloc((size_t)N * 32 * 2);
    float* r2      = (float*)alloc((size_t)N * 32 * 4);

    const int* idx = (const int*)d_in[1];
    const int egrid = (E + 255) / 256;

    detect_kernel<<<1, 64, 0, stream>>>((const u16*)d_in[0], (const u32*)d_in[1], flags);
    hipMemsetAsync(cnt, 0, (size_t)N * 4, stream);
    hist_kernel<<<egrid, 256, 0, stream>>>(idx, flags, cnt, within, E);
    scan_kernel<<<1, SCAN_THREADS, 0, stream>>>(cnt, row_ptr, N);
    scatter_kernel<<<egrid, 256, 0, stream>>>(idx, flags, row_ptr, within, ssrc, E);

    // layer-1 aggregation of raw x (A1 stored bf16 in bf16 mode)
    agg_kernel<u16, u16, 64><<<2048, 256, 0, stream>>>((const u16*)d_in[0], row_ptr, ssrc,
                                                       (u16*)A1, flags, N, 1);
    agg_kernel<float, float, 64><<<2048, 256, 0, stream>>>((const float*)d_in[0], row_ptr, ssrc,
                                                           (float*)A1, flags, N, 0);

    // layer-1 transform
    layer1_mfma_kernel<<<(N + 63) / 64, 256, 0, stream>>>((const u16*)A1, (const u16*)d_in[0],
        (const u16*)d_in[2], (const u16*)d_in[3], (const u16*)d_in[4],
        (const u16*)d_in[5], (const u16*)d_in[6], (const u16*)d_in[7],
        z2, r2, flags, N);
    layer1_f32_kernel<<<1024, 256, 0, stream>>>((const float*)A1, (const float*)d_in[0],
        (const float*)d_in[2], (const float*)d_in[3], (const float*)d_in[4],
        (const float*)d_in[5], (const float*)d_in[6], (const float*)d_in[7],
        z2, r2, flags, N);

    // fused layer-2 aggregation + final linear
    layer2_final_kernel<u16, u16><<<2048, 256, 0, stream>>>(z2, r2, row_ptr, ssrc,
        (const u16*)d_in[8], (const u16*)d_in[9], (u16*)d_out, flags, N, 1);
    layer2_final_kernel<float, float><<<2048, 256, 0, stream>>>(z2, r2, row_ptr, ssrc,
        (const float*)d_in[8], (const float*)d_in[9], (float*)d_out, flags, N, 0);
}

// Round 4
// 345.963 us; speedup vs baseline: 1.2080x; 1.2080x over previous
//
#include <hip/hip_runtime.h>
#include <cstdint>
#include <cstddef>

using u16 = unsigned short;
using u32 = unsigned int;

typedef short short8 __attribute__((ext_vector_type(8)));
typedef float f32x4 __attribute__((ext_vector_type(4)));

// ---------- bf16 helpers ----------
__device__ __forceinline__ float bf2f(u16 h) { return __uint_as_float(((u32)h) << 16); }
__device__ __forceinline__ u16 f2bf(float f) {
    u32 u = __float_as_uint(f);
    u += 0x7FFFu + ((u >> 16) & 1u);   // RNE
    return (u16)(u >> 16);
}

// load/store 8 contiguous elements (16B-aligned at all call sites)
__device__ __forceinline__ void load8(const float* p, float* v) {
    float4 a = ((const float4*)p)[0];
    float4 b = ((const float4*)p)[1];
    v[0]=a.x; v[1]=a.y; v[2]=a.z; v[3]=a.w;
    v[4]=b.x; v[5]=b.y; v[6]=b.z; v[7]=b.w;
}
__device__ __forceinline__ void load8(const u16* p, float* v) {
    uint4 u = *(const uint4*)p;
    v[0]=__uint_as_float(u.x << 16); v[1]=__uint_as_float(u.x & 0xFFFF0000u);
    v[2]=__uint_as_float(u.y << 16); v[3]=__uint_as_float(u.y & 0xFFFF0000u);
    v[4]=__uint_as_float(u.z << 16); v[5]=__uint_as_float(u.z & 0xFFFF0000u);
    v[6]=__uint_as_float(u.w << 16); v[7]=__uint_as_float(u.w & 0xFFFF0000u);
}
__device__ __forceinline__ void store8bf(u16* p, const float* v) {
    uint4 w;
    w.x = (u32)f2bf(v[0]) | ((u32)f2bf(v[1]) << 16);
    w.y = (u32)f2bf(v[2]) | ((u32)f2bf(v[3]) << 16);
    w.z = (u32)f2bf(v[4]) | ((u32)f2bf(v[5]) << 16);
    w.w = (u32)f2bf(v[6]) | ((u32)f2bf(v[7]) << 16);
    *(uint4*)p = w;
}
__device__ __forceinline__ short8 ld8b(const u16* p) {
    union { uint4 u; short8 s; } c;
    c.u = *(const uint4*)p;
    return c.s;
}

// ---------- 0. edge-index stride detection (int64 vs int32 insurance) ----------
__global__ __launch_bounds__(64) void detect_kernel(const u32* idxraw, int* flags) {
    if (threadIdx.x == 0 && blockIdx.x == 0) {
        int nz = 0;
        for (int i = 1; i < 256; i += 2) if (idxraw[i] != 0u) nz++;
        flags[1] = (nz == 0) ? 2 : 1;       // all-high-words-zero -> int64
    }
}

// ---------- 0b. split x into bf16 hi/lo ----------
__global__ __launch_bounds__(256) void split_x_kernel(const float* __restrict__ x,
                                                      u16* __restrict__ xh,
                                                      u16* __restrict__ xl, int total8) {
    const int c = blockIdx.x * blockDim.x + threadIdx.x;
    if (c >= total8) return;
    float v[8], lo[8];
    load8(x + (size_t)c * 8, v);
    #pragma unroll
    for (int k = 0; k < 8; ++k) lo[k] = v[k] - bf2f(f2bf(v[k]));
    store8bf(xh + (size_t)c * 8, v);
    store8bf(xl + (size_t)c * 8, lo);
}

// ---------- 1. CSR build (atomic decoupled from the scatter store) ----------
__global__ __launch_bounds__(256) void hist_kernel(const int* idx, const int* __restrict__ flags,
                                                   int* cnt, int* within, int E) {
    const int e = blockIdx.x * blockDim.x + threadIdx.x;
    if (e >= E) return;
    const int stride = flags[1];
    const int d = idx[(size_t)(E + e) * stride];
    within[e] = atomicAdd(&cnt[d], 1);
}

#define SCAN_THREADS 1024
__global__ __launch_bounds__(SCAN_THREADS) void scan_kernel(const int* __restrict__ cnt,
                                                            int* row_ptr, int n) {
    __shared__ int sums[SCAN_THREADS];
    const int tid = threadIdx.x;
    const int chunk = (n + SCAN_THREADS - 1) / SCAN_THREADS;
    const int begin = tid * chunk;
    const int end = min(begin + chunk, n);
    int s = 0;
    for (int i = begin; i < end; ++i) s += cnt[i];
    sums[tid] = s;
    __syncthreads();
    for (int off = 1; off < SCAN_THREADS; off <<= 1) {
        int v = (tid >= off) ? sums[tid - off] : 0;
        __syncthreads();
        sums[tid] += v;
        __syncthreads();
    }
    int run = (tid == 0) ? 0 : sums[tid - 1];
    for (int i = begin; i < end; ++i) { row_ptr[i] = run; run += cnt[i]; }
    if (end == n) row_ptr[n] = run;
}

__global__ __launch_bounds__(256) void scatter_kernel(const int* idx, const int* __restrict__ flags,
                                                      const int* __restrict__ row_ptr,
                                                      const int* __restrict__ within,
                                                      int* ssrc, int E) {
    const int e = blockIdx.x * blockDim.x + threadIdx.x;
    if (e >= E) return;
    const int stride = flags[1];
    const int s = idx[(size_t)e * stride];
    const int d = idx[(size_t)(E + e) * stride];
    ssrc[row_ptr[d] + within[e]] = s;
}

// ---------- 2. layer-1 mean aggregation: gather xh (bf16, 128B rows) -> A1 bf16 ----------
// (bf16 input rounding + bf16 A1 storage wash out under the deg~32 mean; error <<1e-3.)
__global__ __launch_bounds__(256) void agg64_kernel(const u16* __restrict__ feat,
                                                    const int* __restrict__ row_ptr,
                                                    const int* __restrict__ ssrc,
                                                    u16* __restrict__ out, int n) {
    const int lane = threadIdx.x & 63;
    const int wid = (blockIdx.x * blockDim.x + threadIdx.x) >> 6;
    const int nw = (gridDim.x * blockDim.x) >> 6;
    const int g = lane >> 3;        // 8 edge slots per wave
    const int q = lane & 7;         // feature octet
    for (int i = wid; i < n; i += nw) {
        const int rb = row_ptr[i], re = row_ptr[i + 1];
        float acc[8];
        #pragma unroll
        for (int k = 0; k < 8; ++k) acc[k] = 0.f;
        for (int e = rb + g; e < re; e += 8) {
            int s = ssrc[e];
            float v[8];
            load8(feat + (size_t)s * 64 + q * 8, v);
            #pragma unroll
            for (int k = 0; k < 8; ++k) acc[k] += v[k];
        }
        #pragma unroll
        for (int m = 8; m < 64; m <<= 1) {
            #pragma unroll
            for (int k = 0; k < 8; ++k) acc[k] += __shfl_xor(acc[k], m, 64);
        }
        if (g == 0) {
            float inv = 1.0f / (float)max(re - rb, 1);
            #pragma unroll
            for (int k = 0; k < 8; ++k) acc[k] *= inv;
            store8bf(out + (size_t)i * 64 + q * 8, acc);
        }
    }
}

// ---------- 3. layer-1 MFMA (hi/lo split bf16 ~= f32 precision) ----------
// h1 = relu([A1|x] @ [W1l|W1r].T + b1); z2 = bf16(h1@W2l.T); r2 = b2 + h1@W2r.T
// Block = 4 waves = 64 nodes. mfma_f32_16x16x32_bf16 layouts (m89/m91/m120):
//   A[m=lane&15][k=quad*8+j], B[n=lane&15][k=quad*8+j], D col=lane&15, row=quad*4+reg.
#define W1P 140   // row stride u16 (128 k + 12 pad; 70 words % 32 = 6 -> conflict-free starts)
#define W2P 76    // 64 k + 12 pad; 38 words % 32 = 6
__global__ __launch_bounds__(256) void layer1_mfma_kernel(
    const u16* __restrict__ A1b, const u16* __restrict__ xh, const u16* __restrict__ xl,
    const float* __restrict__ W1l, const float* __restrict__ b1,
    const float* __restrict__ W1r, const float* __restrict__ W2l,
    const float* __restrict__ b2, const float* __restrict__ W2r,
    u16* __restrict__ z2, float* __restrict__ r2, int n)
{
    __shared__ alignas(16) u16 w1h[64 * W1P], w1l[64 * W1P];
    __shared__ alignas(16) u16 w2h[64 * W2P], w2l[64 * W2P];
    __shared__ alignas(16) u16 h1h[64 * W2P], h1l[64 * W2P];

    const int t = threadIdx.x;
    // stage + split weights: w1[ch][k<64]=W1l, [64+k]=W1r; w2[ch<32]=W2l, [ch-32]=W2r
    for (int c = t; c < 64 * 32; c += 256) {        // 2048 float4 chunks
        const int ch = c >> 5, k = (c & 31) * 4;
        const float* src = (k < 64) ? (W1l + ch * 64 + k) : (W1r + ch * 64 + (k - 64));
        float4 w = *(const float4*)src;
        const float wv[4] = {w.x, w.y, w.z, w.w};
        #pragma unroll
        for (int j = 0; j < 4; ++j) {
            u16 h = f2bf(wv[j]);
            w1h[ch * W1P + k + j] = h;
            w1l[ch * W1P + k + j] = f2bf(wv[j] - bf2f(h));
        }
    }
    for (int c = t; c < 64 * 16; c += 256) {        // 1024 float4 chunks
        const int ch = c >> 4, k = (c & 15) * 4;
        const float* src = (ch < 32) ? (W2l + ch * 64 + k) : (W2r + (ch - 32) * 64 + k);
        float4 w = *(const float4*)src;
        const float wv[4] = {w.x, w.y, w.z, w.w};
        #pragma unroll
        for (int j = 0; j < 4; ++j) {
            u16 h = f2bf(wv[j]);
            w2h[ch * W2P + k + j] = h;
            w2l[ch * W2P + k + j] = f2bf(wv[j] - bf2f(h));
        }
    }
    __syncthreads();

    const int lane = t & 63;
    const int wv = t >> 6;
    const int m = lane & 15, quad = lane >> 4;
    const int base = blockIdx.x * 64 + wv * 16;

    // A fragments (node rows, clamped; stores are guarded)
    const int nodeA = min(base + m, n - 1);
    const u16* a1row = A1b + (size_t)nodeA * 64;
    const u16* xhrow = xh + (size_t)nodeA * 64;
    const u16* xlrow = xl + (size_t)nodeA * 64;
    short8 aA[2], aH[2], aL[2];
    aA[0] = ld8b(a1row + quad * 8);      aA[1] = ld8b(a1row + 32 + quad * 8);
    aH[0] = ld8b(xhrow + quad * 8);      aH[1] = ld8b(xhrow + 32 + quad * 8);
    aL[0] = ld8b(xlrow + quad * 8);      aL[1] = ld8b(xlrow + 32 + quad * 8);

    // GEMM1 -> h1 (hi/lo) into wave-private LDS rows
    #pragma unroll
    for (int ni = 0; ni < 4; ++ni) {
        const int row = ni * 16 + m;
        f32x4 acc = {0.f, 0.f, 0.f, 0.f};
        #pragma unroll
        for (int kc = 0; kc < 2; ++kc) {            // A1 part (k 0..63): hi-only
            short8 b = ld8b(&w1h[row * W1P + kc * 32 + quad * 8]);
            acc = __builtin_amdgcn_mfma_f32_16x16x32_bf16(aA[kc], b, acc, 0, 0, 0);
        }
        #pragma unroll
        for (int kc = 0; kc < 2; ++kc) {            // x part (k 64..127): split
            short8 bh = ld8b(&w1h[row * W1P + 64 + kc * 32 + quad * 8]);
            short8 bl = ld8b(&w1l[row * W1P + 64 + kc * 32 + quad * 8]);
            acc = __builtin_amdgcn_mfma_f32_16x16x32_bf16(aH[kc], bh, acc, 0, 0, 0);
            acc = __builtin_amdgcn_mfma_f32_16x16x32_bf16(aH[kc], bl, acc, 0, 0, 0);
            acc = __builtin_amdgcn_mfma_f32_16x16x32_bf16(aL[kc], bh, acc, 0, 0, 0);
        }
        const float bias = b1[row];
        #pragma unroll
        for (int r = 0; r < 4; ++r) {
            float h = fmaxf(acc[r] + bias, 0.0f);
            u16 hh = f2bf(h);
            h1h[(wv * 16 + quad * 4 + r) * W2P + row] = hh;
            h1l[(wv * 16 + quad * 4 + r) * W2P + row] = f2bf(h - bf2f(hh));
        }
    }
    // same-wave LDS RAW (wave-private rows): compiler inserts lgkmcnt waits

    short8 ah[2], al[2];
    ah[0] = ld8b(&h1h[(wv * 16 + m) * W2P + quad * 8]);
    ah[1] = ld8b(&h1h[(wv * 16 + m) * W2P + 32 + quad * 8]);
    al[0] = ld8b(&h1l[(wv * 16 + m) * W2P + quad * 8]);
    al[1] = ld8b(&h1l[(wv * 16 + m) * W2P + 32 + quad * 8]);

    #pragma unroll
    for (int ni = 0; ni < 4; ++ni) {
        const int row = ni * 16 + m;
        f32x4 acc = {0.f, 0.f, 0.f, 0.f};
        #pragma unroll
        for (int kc = 0; kc < 2; ++kc) {
            short8 bh = ld8b(&w2h[row * W2P + kc * 32 + quad * 8]);
            short8 bl = ld8b(&w2l[row * W2P + kc * 32 + quad * 8]);
            acc = __builtin_amdgcn_mfma_f32_16x16x32_bf16(ah[kc], bh, acc, 0, 0, 0);
            acc = __builtin_amdgcn_mfma_f32_16x16x32_bf16(ah[kc], bl, acc, 0, 0, 0);
            acc = __builtin_amdgcn_mfma_f32_16x16x32_bf16(al[kc], bh, acc, 0, 0, 0);
        }
        if (ni < 2) {               // z2 channels (no bias), bf16
            #pragma unroll
            for (int r = 0; r < 4; ++r) {
                int node = base + quad * 4 + r;
                if (node < n) z2[(size_t)node * 32 + row] = f2bf(acc[r]);
            }
        } else {                    // r2 channels (+b2), f32
            const int ch = row - 32;
            const float bias = b2[ch];
            #pragma unroll
            for (int r = 0; r < 4; ++r) {
                int node = base + quad * 4 + r;
                if (node < n) r2[(size_t)node * 32 + ch] = acc[r] + bias;
            }
        }
    }
}

// ---------- 4. fused layer-2 agg + epilogue ----------
__global__ __launch_bounds__(256) void layer2_final_kernel(
    const u16* __restrict__ z2, const float* __restrict__ r2,
    const int* __restrict__ row_ptr, const int* __restrict__ ssrc,
    const float* __restrict__ Wlin, const float* __restrict__ blin,
    float* __restrict__ out, int n)
{
    const int lane = threadIdx.x & 63;
    const int wid = (blockIdx.x * blockDim.x + threadIdx.x) >> 6;
    const int nw = (gridDim.x * blockDim.x) >> 6;
    const int g = lane >> 2;    // 16 edge slots per wave
    const int q = lane & 3;     // feature octet
    float wlin8[8];
    load8(Wlin + q * 8, wlin8);
    const float bl = blin[0];
    for (int i = wid; i < n; i += nw) {
        const int rb = row_ptr[i], re = row_ptr[i + 1];
        float acc[8];
        #pragma unroll
        for (int k = 0; k < 8; ++k) acc[k] = 0.f;
        for (int e = rb + g; e < re; e += 16) {
            int s = ssrc[e];
            float v[8];
            load8(z2 + (size_t)s * 32 + q * 8, v);   // one 64B line per edge
            #pragma unroll
            for (int k = 0; k < 8; ++k) acc[k] += v[k];
        }
        #pragma unroll
        for (int m = 4; m < 64; m <<= 1) {
            #pragma unroll
            for (int k = 0; k < 8; ++k) acc[k] += __shfl_xor(acc[k], m, 64);
        }
        float partial = 0.0f;
        if (g == 0) {
            const float inv = 1.0f / (float)max(re - rb, 1);
            float r2v[8];
            load8(r2 + (size_t)i * 32 + q * 8, r2v);
            #pragma unroll
            for (int k = 0; k < 8; ++k)
                partial += fmaxf(fmaf(acc[k], inv, r2v[k]), 0.0f) * wlin8[k];
        }
        partial += __shfl_xor(partial, 1, 64);
        partial += __shfl_xor(partial, 2, 64);
        if (lane == 0) out[i] = partial + bl;
    }
}

// ---------- host ----------
extern "C" void kernel_launch(void* const* d_in, const int* in_sizes, int n_in,
                              void* d_out, int out_size, void* d_ws, size_t ws_size,
                              hipStream_t stream) {
    (void)n_in; (void)out_size; (void)ws_size;
    const int N = in_sizes[0] / 64;
    const int E = in_sizes[1] / 2;

    char* ws = (char*)d_ws;
    size_t off = 0;
    auto alloc = [&](size_t bytes) -> void* {
        void* p = ws + off;
        off += (bytes + 255) & ~(size_t)255;
        return p;
    };
    int*   flags   = (int*)alloc(16);
    int*   cnt     = (int*)alloc((size_t)N * 4);
    int*   within  = (int*)alloc((size_t)E * 4);
    int*   row_ptr = (int*)alloc(((size_t)N + 1) * 4);
    int*   ssrc    = (int*)alloc((size_t)E * 4);
    u16*   xh      = (u16*)alloc((size_t)N * 64 * 2);
    u16*   xl      = (u16*)alloc((size_t)N * 64 * 2);
    u16*   A1b     = (u16*)alloc((size_t)N * 64 * 2);
    u16*   z2      = (u16*)alloc((size_t)N * 32 * 2);
    float* r2      = (float*)alloc((size_t)N * 32 * 4);

    const int* idx = (const int*)d_in[1];
    const int egrid = (E + 255) / 256;

    detect_kernel<<<1, 64, 0, stream>>>((const u32*)d_in[1], flags);
    hipMemsetAsync(cnt, 0, (size_t)N * 4, stream);
    split_x_kernel<<<(N * 8 + 255) / 256, 256, 0, stream>>>((const float*)d_in[0], xh, xl, N * 8);
    hist_kernel<<<egrid, 256, 0, stream>>>(idx, flags, cnt, within, E);
    scan_kernel<<<1, SCAN_THREADS, 0, stream>>>(cnt, row_ptr, N);
    scatter_kernel<<<egrid, 256, 0, stream>>>(idx, flags, row_ptr, within, ssrc, E);

    agg64_kernel<<<2048, 256, 0, stream>>>(xh, row_ptr, ssrc, A1b, N);

    layer1_mfma_kernel<<<(N + 63) / 64, 256, 0, stream>>>(A1b, xh, xl,
        (const float*)d_in[2], (const float*)d_in[3], (const float*)d_in[4],
        (const float*)d_in[5], (const float*)d_in[6], (const float*)d_in[7],
        z2, r2, N);

    layer2_final_kernel<<<2048, 256, 0, stream>>>(z2, r2, row_ptr, ssrc,
        (const float*)d_in[8], (const float*)d_in[9], (float*)d_out, N);
}

// Round 5
// 275.033 us; speedup vs baseline: 1.5195x; 1.2579x over previous
//
#include <hip/hip_runtime.h>
#include <cstdint>
#include <cstddef>

using u16 = unsigned short;
using u32 = unsigned int;

typedef short short8 __attribute__((ext_vector_type(8)));
typedef float f32x4 __attribute__((ext_vector_type(4)));

// ---------- bf16 helpers ----------
__device__ __forceinline__ float bf2f(u16 h) { return __uint_as_float(((u32)h) << 16); }
__device__ __forceinline__ u16 f2bf(float f) {
    u32 u = __float_as_uint(f);
    u += 0x7FFFu + ((u >> 16) & 1u);   // RNE
    return (u16)(u >> 16);
}

// load/store 8 contiguous elements (16B-aligned at all call sites)
__device__ __forceinline__ void load8(const float* p, float* v) {
    float4 a = ((const float4*)p)[0];
    float4 b = ((const float4*)p)[1];
    v[0]=a.x; v[1]=a.y; v[2]=a.z; v[3]=a.w;
    v[4]=b.x; v[5]=b.y; v[6]=b.z; v[7]=b.w;
}
__device__ __forceinline__ void load8(const u16* p, float* v) {
    uint4 u = *(const uint4*)p;
    v[0]=__uint_as_float(u.x << 16); v[1]=__uint_as_float(u.x & 0xFFFF0000u);
    v[2]=__uint_as_float(u.y << 16); v[3]=__uint_as_float(u.y & 0xFFFF0000u);
    v[4]=__uint_as_float(u.z << 16); v[5]=__uint_as_float(u.z & 0xFFFF0000u);
    v[6]=__uint_as_float(u.w << 16); v[7]=__uint_as_float(u.w & 0xFFFF0000u);
}
__device__ __forceinline__ void store8bf(u16* p, const float* v) {
    uint4 w;
    w.x = (u32)f2bf(v[0]) | ((u32)f2bf(v[1]) << 16);
    w.y = (u32)f2bf(v[2]) | ((u32)f2bf(v[3]) << 16);
    w.z = (u32)f2bf(v[4]) | ((u32)f2bf(v[5]) << 16);
    w.w = (u32)f2bf(v[6]) | ((u32)f2bf(v[7]) << 16);
    *(uint4*)p = w;
}
__device__ __forceinline__ short8 ld8b(const u16* p) {
    union { uint4 u; short8 s; } c;
    c.u = *(const uint4*)p;
    return c.s;
}

// ---------- 0. edge-index stride detection (int64 vs int32 insurance) ----------
__global__ __launch_bounds__(64) void detect_kernel(const u32* idxraw, int* flags) {
    if (threadIdx.x == 0 && blockIdx.x == 0) {
        int nz = 0;
        for (int i = 1; i < 256; i += 2) if (idxraw[i] != 0u) nz++;
        flags[1] = (nz == 0) ? 2 : 1;       // all-high-words-zero -> int64
    }
}

// ---------- 0b. split x into bf16 hi/lo ----------
__global__ __launch_bounds__(256) void split_x_kernel(const float* __restrict__ x,
                                                      u16* __restrict__ xh,
                                                      u16* __restrict__ xl, int total8) {
    const int c = blockIdx.x * blockDim.x + threadIdx.x;
    if (c >= total8) return;
    float v[8], lo[8];
    load8(x + (size_t)c * 8, v);
    #pragma unroll
    for (int k = 0; k < 8; ++k) lo[k] = v[k] - bf2f(f2bf(v[k]));
    store8bf(xh + (size_t)c * 8, v);
    store8bf(xl + (size_t)c * 8, lo);
}

// ---------- 1. CSR build ----------
__global__ __launch_bounds__(256) void hist_kernel(const int* idx, const int* __restrict__ flags,
                                                   int* cnt, int* within, int E) {
    const int e = blockIdx.x * blockDim.x + threadIdx.x;
    if (e >= E) return;
    const int stride = flags[1];
    const int d = idx[(size_t)(E + e) * stride];
    within[e] = atomicAdd(&cnt[d], 1);
}

// ----- 3-phase scan (replaces the 77 us single-block scan) -----
// A: per-block sums
__global__ __launch_bounds__(256) void scan_partials_kernel(const int* __restrict__ cnt,
                                                            int* __restrict__ bsum, int n) {
    __shared__ int ws[4];
    const int i = blockIdx.x * 256 + threadIdx.x;
    int v = (i < n) ? cnt[i] : 0;
    #pragma unroll
    for (int m = 1; m < 64; m <<= 1) v += __shfl_xor(v, m, 64);
    const int lane = threadIdx.x & 63, wv = threadIdx.x >> 6;
    if (lane == 0) ws[wv] = v;
    __syncthreads();
    if (threadIdx.x == 0) bsum[blockIdx.x] = ws[0] + ws[1] + ws[2] + ws[3];
}
// B: exclusive scan of block sums (nb <= 256, i.e. n <= 65536)
__global__ __launch_bounds__(256) void scan_bsums_kernel(const int* __restrict__ bsum,
                                                         int* __restrict__ boff, int nb) {
    __shared__ int ws[4];
    const int t = threadIdx.x;
    const int lane = t & 63, wv = t >> 6;
    int x = (t < nb) ? bsum[t] : 0;
    int v = x;
    #pragma unroll
    for (int o = 1; o < 64; o <<= 1) {
        int u = __shfl_up(v, o, 64);
        if (lane >= o) v += u;
    }
    if (lane == 63) ws[wv] = v;
    __syncthreads();
    int woff = 0;
    for (int w = 0; w < wv; ++w) woff += ws[w];
    if (t < nb) boff[t] = v + woff - x;     // exclusive
}
// C: block-local exclusive scan + block offset -> row_ptr
__global__ __launch_bounds__(256) void scan_write_kernel(const int* __restrict__ cnt,
                                                         const int* __restrict__ boff,
                                                         int* __restrict__ row_ptr, int n) {
    __shared__ int ws[4];
    const int t = threadIdx.x;
    const int i = blockIdx.x * 256 + t;
    const int lane = t & 63, wv = t >> 6;
    const int x = (i < n) ? cnt[i] : 0;
    int v = x;
    #pragma unroll
    for (int o = 1; o < 64; o <<= 1) {
        int u = __shfl_up(v, o, 64);
        if (lane >= o) v += u;
    }
    if (lane == 63) ws[wv] = v;
    __syncthreads();
    int woff = boff[blockIdx.x];
    for (int w = 0; w < wv; ++w) woff += ws[w];
    const int excl = v - x + woff;
    if (i < n) row_ptr[i] = excl;
    if (i == n - 1) row_ptr[n] = excl + x;
}

__global__ __launch_bounds__(256) void scatter_kernel(const int* idx, const int* __restrict__ flags,
                                                      const int* __restrict__ row_ptr,
                                                      const int* __restrict__ within,
                                                      int* ssrc, int E) {
    const int e = blockIdx.x * blockDim.x + threadIdx.x;
    if (e >= E) return;
    const int stride = flags[1];
    const int s = idx[(size_t)e * stride];
    const int d = idx[(size_t)(E + e) * stride];
    ssrc[row_ptr[d] + within[e]] = s;
}

// ---------- 2. layer-1 mean aggregation: gather xh (bf16, 128B rows) -> A1 bf16 ----------
__global__ __launch_bounds__(256) void agg64_kernel(const u16* __restrict__ feat,
                                                    const int* __restrict__ row_ptr,
                                                    const int* __restrict__ ssrc,
                                                    u16* __restrict__ out, int n) {
    const int lane = threadIdx.x & 63;
    const int wid = (blockIdx.x * blockDim.x + threadIdx.x) >> 6;
    const int nw = (gridDim.x * blockDim.x) >> 6;
    const int g = lane >> 3;        // 8 edge slots per wave
    const int q = lane & 7;         // feature octet
    for (int i = wid; i < n; i += nw) {
        const int rb = row_ptr[i], re = row_ptr[i + 1];
        float acc[8];
        #pragma unroll
        for (int k = 0; k < 8; ++k) acc[k] = 0.f;
        for (int e = rb + g; e < re; e += 8) {
            int s = ssrc[e];
            float v[8];
            load8(feat + (size_t)s * 64 + q * 8, v);
            #pragma unroll
            for (int k = 0; k < 8; ++k) acc[k] += v[k];
        }
        #pragma unroll
        for (int m = 8; m < 64; m <<= 1) {
            #pragma unroll
            for (int k = 0; k < 8; ++k) acc[k] += __shfl_xor(acc[k], m, 64);
        }
        if (g == 0) {
            float inv = 1.0f / (float)max(re - rb, 1);
            #pragma unroll
            for (int k = 0; k < 8; ++k) acc[k] *= inv;
            store8bf(out + (size_t)i * 64 + q * 8, acc);
        }
    }
}

// ---------- 3. layer-1 MFMA (hi/lo split bf16 ~= f32 precision) ----------
#define W1P 140
#define W2P 76
__global__ __launch_bounds__(256) void layer1_mfma_kernel(
    const u16* __restrict__ A1b, const u16* __restrict__ xh, const u16* __restrict__ xl,
    const float* __restrict__ W1l, const float* __restrict__ b1,
    const float* __restrict__ W1r, const float* __restrict__ W2l,
    const float* __restrict__ b2, const float* __restrict__ W2r,
    u16* __restrict__ z2, float* __restrict__ r2, int n)
{
    __shared__ alignas(16) u16 w1h[64 * W1P], w1l[64 * W1P];
    __shared__ alignas(16) u16 w2h[64 * W2P], w2l[64 * W2P];
    __shared__ alignas(16) u16 h1h[64 * W2P], h1l[64 * W2P];

    const int t = threadIdx.x;
    for (int c = t; c < 64 * 32; c += 256) {
        const int ch = c >> 5, k = (c & 31) * 4;
        const float* src = (k < 64) ? (W1l + ch * 64 + k) : (W1r + ch * 64 + (k - 64));
        float4 w = *(const float4*)src;
        const float wv[4] = {w.x, w.y, w.z, w.w};
        #pragma unroll
        for (int j = 0; j < 4; ++j) {
            u16 h = f2bf(wv[j]);
            w1h[ch * W1P + k + j] = h;
            w1l[ch * W1P + k + j] = f2bf(wv[j] - bf2f(h));
        }
    }
    for (int c = t; c < 64 * 16; c += 256) {
        const int ch = c >> 4, k = (c & 15) * 4;
        const float* src = (ch < 32) ? (W2l + ch * 64 + k) : (W2r + (ch - 32) * 64 + k);
        float4 w = *(const float4*)src;
        const float wv[4] = {w.x, w.y, w.z, w.w};
        #pragma unroll
        for (int j = 0; j < 4; ++j) {
            u16 h = f2bf(wv[j]);
            w2h[ch * W2P + k + j] = h;
            w2l[ch * W2P + k + j] = f2bf(wv[j] - bf2f(h));
        }
    }
    __syncthreads();

    const int lane = t & 63;
    const int wv = t >> 6;
    const int m = lane & 15, quad = lane >> 4;
    const int base = blockIdx.x * 64 + wv * 16;

    const int nodeA = min(base + m, n - 1);
    const u16* a1row = A1b + (size_t)nodeA * 64;
    const u16* xhrow = xh + (size_t)nodeA * 64;
    const u16* xlrow = xl + (size_t)nodeA * 64;
    short8 aA[2], aH[2], aL[2];
    aA[0] = ld8b(a1row + quad * 8);      aA[1] = ld8b(a1row + 32 + quad * 8);
    aH[0] = ld8b(xhrow + quad * 8);      aH[1] = ld8b(xhrow + 32 + quad * 8);
    aL[0] = ld8b(xlrow + quad * 8);      aL[1] = ld8b(xlrow + 32 + quad * 8);

    #pragma unroll
    for (int ni = 0; ni < 4; ++ni) {
        const int row = ni * 16 + m;
        f32x4 acc = {0.f, 0.f, 0.f, 0.f};
        #pragma unroll
        for (int kc = 0; kc < 2; ++kc) {
            short8 b = ld8b(&w1h[row * W1P + kc * 32 + quad * 8]);
            acc = __builtin_amdgcn_mfma_f32_16x16x32_bf16(aA[kc], b, acc, 0, 0, 0);
        }
        #pragma unroll
        for (int kc = 0; kc < 2; ++kc) {
            short8 bh = ld8b(&w1h[row * W1P + 64 + kc * 32 + quad * 8]);
            short8 bl = ld8b(&w1l[row * W1P + 64 + kc * 32 + quad * 8]);
            acc = __builtin_amdgcn_mfma_f32_16x16x32_bf16(aH[kc], bh, acc, 0, 0, 0);
            acc = __builtin_amdgcn_mfma_f32_16x16x32_bf16(aH[kc], bl, acc, 0, 0, 0);
            acc = __builtin_amdgcn_mfma_f32_16x16x32_bf16(aL[kc], bh, acc, 0, 0, 0);
        }
        const float bias = b1[row];
        #pragma unroll
        for (int r = 0; r < 4; ++r) {
            float h = fmaxf(acc[r] + bias, 0.0f);
            u16 hh = f2bf(h);
            h1h[(wv * 16 + quad * 4 + r) * W2P + row] = hh;
            h1l[(wv * 16 + quad * 4 + r) * W2P + row] = f2bf(h - bf2f(hh));
        }
    }

    short8 ah[2], al[2];
    ah[0] = ld8b(&h1h[(wv * 16 + m) * W2P + quad * 8]);
    ah[1] = ld8b(&h1h[(wv * 16 + m) * W2P + 32 + quad * 8]);
    al[0] = ld8b(&h1l[(wv * 16 + m) * W2P + quad * 8]);
    al[1] = ld8b(&h1l[(wv * 16 + m) * W2P + 32 + quad * 8]);

    #pragma unroll
    for (int ni = 0; ni < 4; ++ni) {
        const int row = ni * 16 + m;
        f32x4 acc = {0.f, 0.f, 0.f, 0.f};
        #pragma unroll
        for (int kc = 0; kc < 2; ++kc) {
            short8 bh = ld8b(&w2h[row * W2P + kc * 32 + quad * 8]);
            short8 bl = ld8b(&w2l[row * W2P + kc * 32 + quad * 8]);
            acc = __builtin_amdgcn_mfma_f32_16x16x32_bf16(ah[kc], bh, acc, 0, 0, 0);
            acc = __builtin_amdgcn_mfma_f32_16x16x32_bf16(ah[kc], bl, acc, 0, 0, 0);
            acc = __builtin_amdgcn_mfma_f32_16x16x32_bf16(al[kc], bh, acc, 0, 0, 0);
        }
        if (ni < 2) {
            #pragma unroll
            for (int r = 0; r < 4; ++r) {
                int node = base + quad * 4 + r;
                if (node < n) z2[(size_t)node * 32 + row] = f2bf(acc[r]);
            }
        } else {
            const int ch = row - 32;
            const float bias = b2[ch];
            #pragma unroll
            for (int r = 0; r < 4; ++r) {
                int node = base + quad * 4 + r;
                if (node < n) r2[(size_t)node * 32 + ch] = acc[r] + bias;
            }
        }
    }
}

// ---------- 4. fused layer-2 agg + epilogue ----------
__global__ __launch_bounds__(256) void layer2_final_kernel(
    const u16* __restrict__ z2, const float* __restrict__ r2,
    const int* __restrict__ row_ptr, const int* __restrict__ ssrc,
    const float* __restrict__ Wlin, const float* __restrict__ blin,
    float* __restrict__ out, int n)
{
    const int lane = threadIdx.x & 63;
    const int wid = (blockIdx.x * blockDim.x + threadIdx.x) >> 6;
    const int nw = (gridDim.x * blockDim.x) >> 6;
    const int g = lane >> 2;
    const int q = lane & 3;
    float wlin8[8];
    load8(Wlin + q * 8, wlin8);
    const float bl = blin[0];
    for (int i = wid; i < n; i += nw) {
        const int rb = row_ptr[i], re = row_ptr[i + 1];
        float acc[8];
        #pragma unroll
        for (int k = 0; k < 8; ++k) acc[k] = 0.f;
        for (int e = rb + g; e < re; e += 16) {
            int s = ssrc[e];
            float v[8];
            load8(z2 + (size_t)s * 32 + q * 8, v);
            #pragma unroll
            for (int k = 0; k < 8; ++k) acc[k] += v[k];
        }
        #pragma unroll
        for (int m = 4; m < 64; m <<= 1) {
            #pragma unroll
            for (int k = 0; k < 8; ++k) acc[k] += __shfl_xor(acc[k], m, 64);
        }
        float partial = 0.0f;
        if (g == 0) {
            const float inv = 1.0f / (float)max(re - rb, 1);
            float r2v[8];
            load8(r2 + (size_t)i * 32 + q * 8, r2v);
            #pragma unroll
            for (int k = 0; k < 8; ++k)
                partial += fmaxf(fmaf(acc[k], inv, r2v[k]), 0.0f) * wlin8[k];
        }
        partial += __shfl_xor(partial, 1, 64);
        partial += __shfl_xor(partial, 2, 64);
        if (lane == 0) out[i] = partial + bl;
    }
}

// ---------- host ----------
extern "C" void kernel_launch(void* const* d_in, const int* in_sizes, int n_in,
                              void* d_out, int out_size, void* d_ws, size_t ws_size,
                              hipStream_t stream) {
    (void)n_in; (void)out_size; (void)ws_size;
    const int N = in_sizes[0] / 64;
    const int E = in_sizes[1] / 2;

    char* ws = (char*)d_ws;
    size_t off = 0;
    auto alloc = [&](size_t bytes) -> void* {
        void* p = ws + off;
        off += (bytes + 255) & ~(size_t)255;
        return p;
    };
    int*   flags   = (int*)alloc(16);
    int*   cnt     = (int*)alloc((size_t)N * 4);
    int*   within  = (int*)alloc((size_t)E * 4);
    int*   row_ptr = (int*)alloc(((size_t)N + 1) * 4);
    int*   ssrc    = (int*)alloc((size_t)E * 4);
    int*   bsum    = (int*)alloc(1024);
    int*   boff    = (int*)alloc(1024);
    u16*   xh      = (u16*)alloc((size_t)N * 64 * 2);
    u16*   xl      = (u16*)alloc((size_t)N * 64 * 2);
    u16*   A1b     = (u16*)alloc((size_t)N * 64 * 2);
    u16*   z2      = (u16*)alloc((size_t)N * 32 * 2);
    float* r2      = (float*)alloc((size_t)N * 32 * 4);

    const int* idx = (const int*)d_in[1];
    const int egrid = (E + 255) / 256;
    const int nb = (N + 255) / 256;

    detect_kernel<<<1, 64, 0, stream>>>((const u32*)d_in[1], flags);
    hipMemsetAsync(cnt, 0, (size_t)N * 4, stream);
    split_x_kernel<<<(N * 8 + 255) / 256, 256, 0, stream>>>((const float*)d_in[0], xh, xl, N * 8);
    hist_kernel<<<egrid, 256, 0, stream>>>(idx, flags, cnt, within, E);
    scan_partials_kernel<<<nb, 256, 0, stream>>>(cnt, bsum, N);
    scan_bsums_kernel<<<1, 256, 0, stream>>>(bsum, boff, nb);
    scan_write_kernel<<<nb, 256, 0, stream>>>(cnt, boff, row_ptr, N);
    scatter_kernel<<<egrid, 256, 0, stream>>>(idx, flags, row_ptr, within, ssrc, E);

    agg64_kernel<<<2048, 256, 0, stream>>>(xh, row_ptr, ssrc, A1b, N);

    layer1_mfma_kernel<<<(N + 63) / 64, 256, 0, stream>>>(A1b, xh, xl,
        (const float*)d_in[2], (const float*)d_in[3], (const float*)d_in[4],
        (const float*)d_in[5], (const float*)d_in[6], (const float*)d_in[7],
        z2, r2, N);

    layer2_final_kernel<<<2048, 256, 0, stream>>>(z2, r2, row_ptr, ssrc,
        (const float*)d_in[8], (const float*)d_in[9], (float*)d_out, N);
}